// Round 5
// baseline (317.428 us; speedup 1.0000x reference)
//
#include <hip/hip_runtime.h>
#include <math.h>

#define E_TOT   640000
#define NN      20000
#define DIM     128
#define EDGE_DIM 16

typedef float f32x4 __attribute__((ext_vector_type(4)));
typedef float f32x2 __attribute__((ext_vector_type(2)));
typedef short s16x8 __attribute__((ext_vector_type(8)));
typedef unsigned u32x4 __attribute__((ext_vector_type(4)));
typedef __bf16 bfx8 __attribute__((ext_vector_type(8)));

__device__ __forceinline__ unsigned short f2bf(float f) {
    unsigned u = __builtin_bit_cast(unsigned, f);
    u += 0x7fffu + ((u >> 16) & 1u);
    return (unsigned short)(u >> 16);
}
__device__ __forceinline__ unsigned cvt_pk_bf16(float lo, float hi) {
    unsigned r;
    asm("v_cvt_pk_bf16_f32 %0, %1, %2" : "=v"(r) : "v"(lo), "v"(hi));
    return r;
}
__device__ __forceinline__ float silu_f(float x)    { return x / (1.0f + __expf(-x)); }
__device__ __forceinline__ float sigmoid_f(float x) { return 1.0f / (1.0f + __expf(-x)); }

#define MFMA16(a, b, c) __builtin_amdgcn_mfma_f32_16x16x32_bf16( \
    __builtin_bit_cast(bfx8, (a)), __builtin_bit_cast(bfx8, (b)), (c), 0, 0, 0)

// ---------------------------------------------------------------------------
// mega-prep: h->bf16, 4 weight packs (pair-permuted fragment-major), zero
// agg and cnts. One launch.
// Pack layout: Wp[(sg*128 + f*16 + q)*8 + t] = W[k = sg*8+t][col], col =
// (f>>1)*32 + 2q + (f&1); zero-padded for k >= K.
// ---------------------------------------------------------------------------
__device__ __forceinline__ void pack_w(const float* __restrict__ W,
                                       unsigned short* __restrict__ Wp,
                                       int K, int id) {
    int t   = id & 7;
    int pos = (id >> 3) & 127;
    int sg  = id >> 10;
    int qq = pos & 15, f = pos >> 4;
    int col = (f >> 1) * 32 + 2 * qq + (f & 1);
    int k = sg * 8 + t;
    Wp[id] = (k < K) ? f2bf(W[(size_t)k * DIM + col]) : (unsigned short)0;
}

__global__ void prep_all_kernel(const float* __restrict__ h,
                                unsigned short* __restrict__ h_bf,
                                const float* __restrict__ Wm1,
                                const float* __restrict__ Wm2,
                                const float* __restrict__ Wn1,
                                const float* __restrict__ Wn2,
                                unsigned short* __restrict__ W1p,
                                unsigned short* __restrict__ W2p,
                                unsigned short* __restrict__ Wn1p,
                                unsigned short* __restrict__ Wn2p,
                                float* __restrict__ agg,
                                int* __restrict__ cnts) {
    const int blk = blockIdx.x;
    const int tid = threadIdx.x;
    if (blk < 2500) {                       // h -> bf16 (640000 f32x4)
        int i = blk * 256 + tid;
        float4 v = reinterpret_cast<const float4*>(h)[i];
        unsigned short* d = h_bf + i * 4;
        d[0] = f2bf(v.x); d[1] = f2bf(v.y); d[2] = f2bf(v.z); d[3] = f2bf(v.w);
    } else if (blk < 2644) {                // W1p: 288x128
        pack_w(Wm1, W1p, 272, (blk - 2500) * 256 + tid);
    } else if (blk < 2708) {                // W2p: 128x128
        pack_w(Wm2, W2p, 128, (blk - 2644) * 256 + tid);
    } else if (blk < 2836) {                // Wn1p: 256x128
        pack_w(Wn1, Wn1p, 256, (blk - 2708) * 256 + tid);
    } else if (blk < 2900) {                // Wn2p: 128x128
        pack_w(Wn2, Wn2p, 128, (blk - 2836) * 256 + tid);
    } else if (blk < 5400) {                // zero agg (640000 f32x4)
        int i = (blk - 2900) * 256 + tid;
        reinterpret_cast<f32x4*>(agg)[i] = (f32x4)0.f;
    } else {                                // zero cnts (20000 ints)
        int i = (blk - 5400) * 256 + tid;
        if (i < NN) cnts[i] = 0;
    }
}

// ---------------------------------------------------------------------------
// counting sort of edges by row
// ---------------------------------------------------------------------------
__global__ void hist_kernel(const int* __restrict__ ei, int* __restrict__ counts) {
    int e = blockIdx.x * blockDim.x + threadIdx.x;
    if (e < E_TOT) atomicAdd(&counts[ei[e]], 1);
}

__global__ __launch_bounds__(1024) void scan_kernel(int* __restrict__ counts) {
    __shared__ int s[1024];
    const int tid = threadIdx.x;
    const int CH = 20;
    int base = tid * CH;
    int loc[CH];
    int sum = 0;
    #pragma unroll
    for (int i = 0; i < CH; ++i) {
        int idx = base + i;
        loc[i] = (idx < NN) ? counts[idx] : 0;
        sum += loc[i];
    }
    s[tid] = sum;
    __syncthreads();
    for (int off = 1; off < 1024; off <<= 1) {
        int v = (tid >= off) ? s[tid - off] : 0;
        __syncthreads();
        s[tid] += v;
        __syncthreads();
    }
    int run = s[tid] - sum;
    #pragma unroll
    for (int i = 0; i < CH; ++i) {
        int idx = base + i;
        if (idx < NN) counts[idx] = run;
        run += loc[i];
    }
}

__global__ void scatter_kernel(const int* __restrict__ ei, int* __restrict__ cursor,
                               int* __restrict__ eidS, unsigned short* __restrict__ rowS) {
    int e = blockIdx.x * blockDim.x + threadIdx.x;
    if (e < E_TOT) {
        int r = ei[e];
        int p = atomicAdd(&cursor[r], 1);
        eidS[p] = e;
        rowS[p] = (unsigned short)r;
    }
}

// ---------------------------------------------------------------------------
// Edge kernel: 64 edges/block, 4 independent waves; wave owns 16 edges x all
// 128 cols. A-fragments gathered directly from global (no redundancy across
// waves); weights uniform loads; s_H / s_msg are wave-private (NO barriers).
// Segmented reduction over sorted rows via v_readlane scalar branches.
// ---------------------------------------------------------------------------
template<bool SORTED>
__global__ __launch_bounds__(256, 4) void edge_kernel(
    const unsigned short* __restrict__ h_bf,
    const int* __restrict__ ei,
    const int* __restrict__ eidS,
    const unsigned short* __restrict__ rowS,
    const float* __restrict__ ea,
    const float* __restrict__ emask,
    const unsigned short* __restrict__ W1p,  // 288x128 packed (pair-permuted)
    const float* __restrict__ bm1,
    const unsigned short* __restrict__ W2p,  // 128x128 packed (pair-permuted)
    const float* __restrict__ bm2,
    const float* __restrict__ Wa, const float* __restrict__ ba,
    float* __restrict__ agg)
{
    __shared__ __align__(16) unsigned char s_u[4][4352];  // per-wave region

    const int tid  = threadIdx.x;
    const int wv   = tid >> 6;
    const int lane = tid & 63;
    const int q    = lane & 15;
    const int g    = lane >> 4;
    const int e0w  = blockIdx.x * 64 + wv * 16;

    // per-lane meta for edge q of this wave
    const int   eid  = SORTED ? eidS[e0w + q] : (e0w + q);
    const int   row  = SORTED ? (int)rowS[e0w + q] : ei[eid];
    const int   col  = ei[E_TOT + eid];
    const float mask = emask[eid];

    const char* hb8 = reinterpret_cast<const char*>(h_bf);
    const unsigned rbo = (unsigned)row * 256u + g * 16u;
    const unsigned cbo = (unsigned)col * 256u + g * 16u;

    f32x4 acc[8];
    #pragma unroll
    for (int f = 0; f < 8; ++f) acc[f] = (f32x4)0.f;

    // ---------------- layer 1: k = 0..255 (h[row] | h[col]) ----------------
    #pragma unroll
    for (int s = 0; s < 8; ++s) {
        unsigned off = ((s < 4) ? rbo : cbo) + (s & 3) * 64;
        s16x8 a = *reinterpret_cast<const s16x8*>(hb8 + off);
        #pragma unroll
        for (int f = 0; f < 8; ++f) {
            s16x8 b = *reinterpret_cast<const s16x8*>(
                W1p + ((s * 4 + g) * DIM + f * 16 + q) * 8);
            acc[f] = MFMA16(a, b, acc[f]);
        }
    }
    // k = 256..287: edge_attr (g<2), zero-pad handled by zero A + zero W rows
    {
        s16x8 a = (s16x8)0;
        if (g < 2) {
            const float4* pe = reinterpret_cast<const float4*>(
                ea + (size_t)eid * EDGE_DIM + g * 8);
            float4 u = pe[0], v = pe[1];
            u32x4 pk;
            pk[0] = cvt_pk_bf16(u.x, u.y); pk[1] = cvt_pk_bf16(u.z, u.w);
            pk[2] = cvt_pk_bf16(v.x, v.y); pk[3] = cvt_pk_bf16(v.z, v.w);
            a = __builtin_bit_cast(s16x8, pk);
        }
        #pragma unroll
        for (int f = 0; f < 8; ++f) {
            s16x8 b = *reinterpret_cast<const s16x8*>(
                W1p + ((32 + g) * DIM + f * 16 + q) * 8);
            acc[f] = MFMA16(a, b, acc[f]);
        }
    }

    // bias + silu -> wave-private s_H (packed pair writes)
    unsigned char* sw = s_u[wv];
    {
        #pragma unroll
        for (int aa = 0; aa < 4; ++aa) {
            f32x2 bp = *reinterpret_cast<const f32x2*>(bm1 + aa * 32 + 2 * q);
            #pragma unroll
            for (int r = 0; r < 4; ++r) {
                float v0 = silu_f(acc[2 * aa][r] + bp.x);
                float v1 = silu_f(acc[2 * aa + 1][r] + bp.y);
                *reinterpret_cast<unsigned*>(
                    sw + (g * 4 + r) * 272 + aa * 64 + 4 * q) = cvt_pk_bf16(v0, v1);
            }
        }
    }
    // same-wave LDS RAW: compiler inserts lgkmcnt wait; no barrier needed

    // ---------------- layer 2: k = 0..127 ----------------
    f32x4 acc2[8];
    #pragma unroll
    for (int f = 0; f < 8; ++f) acc2[f] = (f32x4)0.f;

    #pragma unroll
    for (int s = 0; s < 4; ++s) {
        s16x8 a = *reinterpret_cast<const s16x8*>(sw + q * 272 + s * 64 + g * 16);
        #pragma unroll
        for (int f = 0; f < 8; ++f) {
            s16x8 b = *reinterpret_cast<const s16x8*>(
                W2p + ((s * 4 + g) * DIM + f * 16 + q) * 8);
            acc2[f] = MFMA16(a, b, acc2[f]);
        }
    }

    // bias + silu; attention dot (16-lane shfl reduce); sigmoid*mask; scale;
    // pack scaled messages -> wave-private s_msg[16][66] (u32 pairs)
    {
        f32x2 b2[4], wa[4];
        #pragma unroll
        for (int aa = 0; aa < 4; ++aa) {
            b2[aa] = *reinterpret_cast<const f32x2*>(bm2 + aa * 32 + 2 * q);
            wa[aa] = *reinterpret_cast<const f32x2*>(Wa  + aa * 32 + 2 * q);
        }
        const float ba0 = ba[0];
        #pragma unroll
        for (int r = 0; r < 4; ++r) {
            float p = 0.f;
            #pragma unroll
            for (int aa = 0; aa < 4; ++aa) {
                float v0 = silu_f(acc2[2 * aa][r] + b2[aa].x);
                float v1 = silu_f(acc2[2 * aa + 1][r] + b2[aa].y);
                acc2[2 * aa][r] = v0; acc2[2 * aa + 1][r] = v1;
                p = fmaf(v0, wa[aa].x, fmaf(v1, wa[aa].y, p));
            }
            p += __shfl_xor(p, 1);
            p += __shfl_xor(p, 2);
            p += __shfl_xor(p, 4);
            p += __shfl_xor(p, 8);
            float mk = __shfl(mask, 4 * g + r);
            float sc = sigmoid_f(p + ba0) * mk;
            #pragma unroll
            for (int aa = 0; aa < 4; ++aa) {
                unsigned pk = cvt_pk_bf16(acc2[2 * aa][r] * sc,
                                          acc2[2 * aa + 1][r] * sc);
                *reinterpret_cast<unsigned*>(
                    sw + ((g * 4 + r) * 66 + aa * 16 + q) * 4) = pk;
            }
        }
    }

    // segmented run-reduction over the wave's 16 sorted edges.
    // lane = col-pair index p: cols {(p>>4)*32 + 2*(p&15), +1}
    {
        const unsigned* sm = reinterpret_cast<const unsigned*>(sw);
        const int c0 = (lane >> 4) * 32 + 2 * (lane & 15);
        float s0 = 0.f, s1 = 0.f;
        int prow = __builtin_amdgcn_readlane(row, 0);
        #pragma unroll
        for (int j = 0; j < 16; ++j) {
            int rj = __builtin_amdgcn_readlane(row, j);
            if (rj != prow) {                       // wave-uniform branch
                float* dst = agg + (size_t)prow * DIM + c0;
                atomicAdd(dst, s0);
                atomicAdd(dst + 1, s1);
                s0 = 0.f; s1 = 0.f; prow = rj;
            }
            unsigned v = sm[j * 66 + lane];
            s0 += __builtin_bit_cast(float, v << 16);
            s1 += __builtin_bit_cast(float, v & 0xffff0000u);
        }
        float* dst = agg + (size_t)prow * DIM + c0;
        atomicAdd(dst, s0);
        atomicAdd(dst + 1, s1);
    }
}

// ---------------------------------------------------------------------------
// Node kernel: wave-split like edge kernel; wave owns 16 nodes x 128 cols.
// [h | agg] @ Wn1 -> silu -> @Wn2 -> residual -> flags. No barriers.
// ---------------------------------------------------------------------------
__global__ __launch_bounds__(256, 4) void node_kernel(
    const unsigned short* __restrict__ h_bf,
    const float* __restrict__ agg,
    const float* __restrict__ h,
    const float* __restrict__ flags,
    const unsigned short* __restrict__ Wn1p,  // 256x128 packed (pair-permuted)
    const float* __restrict__ bn1,
    const unsigned short* __restrict__ Wn2p,  // 128x128 packed (pair-permuted)
    const float* __restrict__ bn2,
    float* __restrict__ out)
{
    __shared__ __align__(16) unsigned char s_u[4][4352];

    const int tid  = threadIdx.x;
    const int wv   = tid >> 6;
    const int lane = tid & 63;
    const int q    = lane & 15;
    const int g    = lane >> 4;
    const int n0w  = blockIdx.x * 64 + wv * 16;

    const int nq  = n0w + q;
    const int nqc = (nq < NN) ? nq : (NN - 1);   // clamp; stores are masked

    f32x4 acc[8];
    #pragma unroll
    for (int f = 0; f < 8; ++f) acc[f] = (f32x4)0.f;

    // k = 0..127: h_bf direct
    #pragma unroll
    for (int s = 0; s < 4; ++s) {
        s16x8 a = *reinterpret_cast<const s16x8*>(
            h_bf + (size_t)nqc * DIM + s * 32 + g * 8);
        #pragma unroll
        for (int f = 0; f < 8; ++f) {
            s16x8 b = *reinterpret_cast<const s16x8*>(
                Wn1p + ((s * 4 + g) * DIM + f * 16 + q) * 8);
            acc[f] = MFMA16(a, b, acc[f]);
        }
    }
    // k = 128..255: agg (f32 -> bf16 in-register)
    #pragma unroll
    for (int s = 4; s < 8; ++s) {
        const float4* pa = reinterpret_cast<const float4*>(
            agg + (size_t)nqc * DIM + (s - 4) * 32 + g * 8);
        float4 u = pa[0], v = pa[1];
        u32x4 pk;
        pk[0] = cvt_pk_bf16(u.x, u.y); pk[1] = cvt_pk_bf16(u.z, u.w);
        pk[2] = cvt_pk_bf16(v.x, v.y); pk[3] = cvt_pk_bf16(v.z, v.w);
        s16x8 a = __builtin_bit_cast(s16x8, pk);
        #pragma unroll
        for (int f = 0; f < 8; ++f) {
            s16x8 b = *reinterpret_cast<const s16x8*>(
                Wn1p + ((s * 4 + g) * DIM + f * 16 + q) * 8);
            acc[f] = MFMA16(a, b, acc[f]);
        }
    }

    unsigned char* sw = s_u[wv];
    {
        #pragma unroll
        for (int aa = 0; aa < 4; ++aa) {
            f32x2 bp = *reinterpret_cast<const f32x2*>(bn1 + aa * 32 + 2 * q);
            #pragma unroll
            for (int r = 0; r < 4; ++r) {
                float v0 = silu_f(acc[2 * aa][r] + bp.x);
                float v1 = silu_f(acc[2 * aa + 1][r] + bp.y);
                *reinterpret_cast<unsigned*>(
                    sw + (g * 4 + r) * 272 + aa * 64 + 4 * q) = cvt_pk_bf16(v0, v1);
            }
        }
    }

    f32x4 acc2[8];
    #pragma unroll
    for (int f = 0; f < 8; ++f) acc2[f] = (f32x4)0.f;

    #pragma unroll
    for (int s = 0; s < 4; ++s) {
        s16x8 a = *reinterpret_cast<const s16x8*>(sw + q * 272 + s * 64 + g * 16);
        #pragma unroll
        for (int f = 0; f < 8; ++f) {
            s16x8 b = *reinterpret_cast<const s16x8*>(
                Wn2p + ((s * 4 + g) * DIM + f * 16 + q) * 8);
            acc2[f] = MFMA16(a, b, acc2[f]);
        }
    }

    {
        #pragma unroll
        for (int r = 0; r < 4; ++r) {
            int n = n0w + 4 * g + r;
            if (n < NN) {
                float fl = flags[n];
                #pragma unroll
                for (int aa = 0; aa < 4; ++aa) {
                    f32x2 b2 = *reinterpret_cast<const f32x2*>(bn2 + aa * 32 + 2 * q);
                    size_t b = (size_t)n * DIM + aa * 32 + 2 * q;
                    f32x2 hv = *reinterpret_cast<const f32x2*>(h + b);
                    f32x2 o;
                    o.x = (hv.x + acc2[2 * aa][r] + b2.x) * fl;
                    o.y = (hv.y + acc2[2 * aa + 1][r] + b2.y) * fl;
                    *reinterpret_cast<f32x2*>(out + b) = o;
                }
            }
        }
    }
}

extern "C" void kernel_launch(void* const* d_in, const int* in_sizes, int n_in,
                              void* d_out, int out_size, void* d_ws, size_t ws_size,
                              hipStream_t stream) {
    const float* h     = (const float*)d_in[0];
    const int*   ei    = (const int*)  d_in[1];
    const float* ea    = (const float*)d_in[2];
    const float* flags = (const float*)d_in[3];
    const float* emask = (const float*)d_in[4];
    const float* Wm1   = (const float*)d_in[5];
    const float* bm1   = (const float*)d_in[6];
    const float* Wm2   = (const float*)d_in[7];
    const float* bm2   = (const float*)d_in[8];
    const float* Wa    = (const float*)d_in[9];
    const float* ba    = (const float*)d_in[10];
    const float* Wn1   = (const float*)d_in[11];
    const float* bn1   = (const float*)d_in[12];
    const float* Wn2   = (const float*)d_in[13];
    const float* bn2   = (const float*)d_in[14];
    float* out = (float*)d_out;

    char* ws = (char*)d_ws;
    float*          agg   = (float*)         (ws);                 // 10,240,000
    unsigned short* h_bf  = (unsigned short*)(ws + 10240000);      //  5,120,000
    unsigned short* W1p   = (unsigned short*)(ws + 15360000);      //     73,728
    unsigned short* W2p   = (unsigned short*)(ws + 15433728);      //     32,768
    unsigned short* Wn1p  = (unsigned short*)(ws + 15466496);      //     65,536
    unsigned short* Wn2p  = (unsigned short*)(ws + 15532032);      //     32,768
    int*            cnts  = (int*)           (ws + 15564800);      //     80,000
    int*            eidS  = (int*)           (ws + 15644800);      //  2,560,000
    unsigned short* rowS  = (unsigned short*)(ws + 18204800);      //  1,280,000
    const size_t WS_NEED = 19484800;

    const bool sorted = (ws_size >= WS_NEED);

    prep_all_kernel<<<5479, 256, 0, stream>>>(h, h_bf, Wm1, Wm2, Wn1, Wn2,
                                              W1p, W2p, Wn1p, Wn2p, agg, cnts);

    if (sorted) {
        hist_kernel<<<(E_TOT + 255) / 256, 256, 0, stream>>>(ei, cnts);
        scan_kernel<<<1, 1024, 0, stream>>>(cnts);
        scatter_kernel<<<(E_TOT + 255) / 256, 256, 0, stream>>>(ei, cnts, eidS, rowS);
        edge_kernel<true><<<E_TOT / 64, 256, 0, stream>>>(
            h_bf, ei, eidS, rowS, ea, emask, W1p, bm1, W2p, bm2, Wa, ba, agg);
    } else {
        edge_kernel<false><<<E_TOT / 64, 256, 0, stream>>>(
            h_bf, ei, eidS, rowS, ea, emask, W1p, bm1, W2p, bm2, Wa, ba, agg);
    }

    node_kernel<<<(NN + 63) / 64, 256, 0, stream>>>(h_bf, agg, h, flags,
                                                    Wn1p, bn1, Wn2p, bn2, out);
}

// Round 6
// 316.968 us; speedup vs baseline: 1.0015x; 1.0015x over previous
//
#include <hip/hip_runtime.h>
#include <math.h>

#define E_TOT   640000
#define NN      20000
#define DIM     128
#define EDGE_DIM 16

typedef float f32x4 __attribute__((ext_vector_type(4)));
typedef float f32x2 __attribute__((ext_vector_type(2)));
typedef short s16x8 __attribute__((ext_vector_type(8)));
typedef unsigned u32x4 __attribute__((ext_vector_type(4)));
typedef __bf16 bfx8 __attribute__((ext_vector_type(8)));

__device__ __forceinline__ unsigned short f2bf(float f) {
    unsigned u = __builtin_bit_cast(unsigned, f);
    u += 0x7fffu + ((u >> 16) & 1u);
    return (unsigned short)(u >> 16);
}
__device__ __forceinline__ unsigned cvt_pk_bf16(float lo, float hi) {
    unsigned r;
    asm("v_cvt_pk_bf16_f32 %0, %1, %2" : "=v"(r) : "v"(lo), "v"(hi));
    return r;
}
__device__ __forceinline__ float silu_f(float x)    { return x / (1.0f + __expf(-x)); }
__device__ __forceinline__ float sigmoid_f(float x) { return 1.0f / (1.0f + __expf(-x)); }

#define MFMA16(a, b, c) __builtin_amdgcn_mfma_f32_16x16x32_bf16( \
    __builtin_bit_cast(bfx8, (a)), __builtin_bit_cast(bfx8, (b)), (c), 0, 0, 0)

// ---------------------------------------------------------------------------
// mega-prep: h->bf16, 4 weight packs (pair-permuted fragment-major), zero
// agg and cnts. Pack: Wp[(sg*128 + f*16 + q)*8 + t] = W[k=sg*8+t][col],
// col = (f>>1)*32 + 2q + (f&1); zero-padded for k >= K.
// ---------------------------------------------------------------------------
__device__ __forceinline__ void pack_w(const float* __restrict__ W,
                                       unsigned short* __restrict__ Wp,
                                       int K, int id) {
    int t   = id & 7;
    int pos = (id >> 3) & 127;
    int sg  = id >> 10;
    int qq = pos & 15, f = pos >> 4;
    int col = (f >> 1) * 32 + 2 * qq + (f & 1);
    int k = sg * 8 + t;
    Wp[id] = (k < K) ? f2bf(W[(size_t)k * DIM + col]) : (unsigned short)0;
}

__global__ void prep_all_kernel(const float* __restrict__ h,
                                unsigned short* __restrict__ h_bf,
                                const float* __restrict__ Wm1,
                                const float* __restrict__ Wm2,
                                const float* __restrict__ Wn1,
                                const float* __restrict__ Wn2,
                                unsigned short* __restrict__ W1p,
                                unsigned short* __restrict__ W2p,
                                unsigned short* __restrict__ Wn1p,
                                unsigned short* __restrict__ Wn2p,
                                float* __restrict__ agg,
                                int* __restrict__ cnts) {
    const int blk = blockIdx.x;
    const int tid = threadIdx.x;
    if (blk < 2500) {                       // h -> bf16 (640000 f32x4)
        int i = blk * 256 + tid;
        float4 v = reinterpret_cast<const float4*>(h)[i];
        unsigned short* d = h_bf + i * 4;
        d[0] = f2bf(v.x); d[1] = f2bf(v.y); d[2] = f2bf(v.z); d[3] = f2bf(v.w);
    } else if (blk < 2644) {                // W1p: 288x128
        pack_w(Wm1, W1p, 272, (blk - 2500) * 256 + tid);
    } else if (blk < 2708) {                // W2p: 128x128
        pack_w(Wm2, W2p, 128, (blk - 2644) * 256 + tid);
    } else if (blk < 2836) {                // Wn1p: 256x128
        pack_w(Wn1, Wn1p, 256, (blk - 2708) * 256 + tid);
    } else if (blk < 2900) {                // Wn2p: 128x128
        pack_w(Wn2, Wn2p, 128, (blk - 2836) * 256 + tid);
    } else if (blk < 5400) {                // zero agg (640000 f32x4)
        int i = (blk - 2900) * 256 + tid;
        reinterpret_cast<f32x4*>(agg)[i] = (f32x4)0.f;
    } else {                                // zero cnts (20000 ints)
        int i = (blk - 5400) * 256 + tid;
        if (i < NN) cnts[i] = 0;
    }
}

// ---------------------------------------------------------------------------
// counting sort of edges by row
// ---------------------------------------------------------------------------
__global__ void hist_kernel(const int* __restrict__ ei, int* __restrict__ counts) {
    int e = blockIdx.x * blockDim.x + threadIdx.x;
    if (e < E_TOT) atomicAdd(&counts[ei[e]], 1);
}

__global__ __launch_bounds__(1024) void scan_kernel(int* __restrict__ counts) {
    __shared__ int s[1024];
    const int tid = threadIdx.x;
    const int CH = 20;
    int base = tid * CH;
    int loc[CH];
    int sum = 0;
    #pragma unroll
    for (int i = 0; i < CH; ++i) {
        int idx = base + i;
        loc[i] = (idx < NN) ? counts[idx] : 0;
        sum += loc[i];
    }
    s[tid] = sum;
    __syncthreads();
    for (int off = 1; off < 1024; off <<= 1) {
        int v = (tid >= off) ? s[tid - off] : 0;
        __syncthreads();
        s[tid] += v;
        __syncthreads();
    }
    int run = s[tid] - sum;
    #pragma unroll
    for (int i = 0; i < CH; ++i) {
        int idx = base + i;
        if (idx < NN) counts[idx] = run;
        run += loc[i];
    }
}

__global__ void scatter_kernel(const int* __restrict__ ei, int* __restrict__ cursor,
                               int* __restrict__ eidS, unsigned short* __restrict__ rowS) {
    int e = blockIdx.x * blockDim.x + threadIdx.x;
    if (e < E_TOT) {
        int r = ei[e];
        int p = atomicAdd(&cursor[r], 1);
        eidS[p] = e;
        rowS[p] = (unsigned short)r;
    }
}

// ---------------------------------------------------------------------------
// Edge kernel: 4 waves/block, wave owns 64 edges x ALL 128 cols.
// acc[4 mi][8 nf] f32x4. A direct from global (unique per wave); B streamed
// from L1/L2 once per 64 edges (4x less traffic than r5). Wave-private
// swizzled s_H (layer1->layer2) and s_msg (scan) in the same 16 KB region.
// ZERO barriers. Segmented run-reduction over 64 sorted edges.
// ---------------------------------------------------------------------------
template<bool SORTED>
__global__ __launch_bounds__(256, 2) void edge_kernel(
    const unsigned short* __restrict__ h_bf,
    const int* __restrict__ ei,
    const int* __restrict__ eidS,
    const unsigned short* __restrict__ rowS,
    const float* __restrict__ ea,
    const float* __restrict__ emask,
    const unsigned short* __restrict__ W1p,  // 288x128 packed (pair-permuted)
    const float* __restrict__ bm1,
    const unsigned short* __restrict__ W2p,  // 128x128 packed (pair-permuted)
    const float* __restrict__ bm2,
    const float* __restrict__ Wa, const float* __restrict__ ba,
    float* __restrict__ agg)
{
    __shared__ __align__(16) unsigned char s_u[4][16384];  // wave-private

    const int tid  = threadIdx.x;
    const int wv   = tid >> 6;
    const int lane = tid & 63;
    const int q    = lane & 15;
    const int g    = lane >> 4;
    const int e0w  = blockIdx.x * 256 + wv * 64;

    // per-lane meta: lane l holds edge (e0w + l)
    const int   eidl = SORTED ? eidS[e0w + lane] : (e0w + lane);
    const int   rowl = SORTED ? (int)rowS[e0w + lane] : ei[eidl];
    const int   coll = ei[E_TOT + eidl];
    const float mskl = emask[eidl];

    // per-mi byte offsets (lane (q,g) computes for edge mi*16+q)
    unsigned rbo[4], cbo[4];
    int eid4[4];
    #pragma unroll
    for (int mi = 0; mi < 4; ++mi) {
        int src = mi * 16 + q;
        rbo[mi]  = (unsigned)__shfl(rowl, src) * 256u + g * 16u;
        cbo[mi]  = (unsigned)__shfl(coll, src) * 256u + g * 16u;
        eid4[mi] = __shfl(eidl, src);
    }
    const char* hb8 = reinterpret_cast<const char*>(h_bf);

    f32x4 acc[4][8];
    #pragma unroll
    for (int mi = 0; mi < 4; ++mi)
        #pragma unroll
        for (int f = 0; f < 8; ++f) acc[mi][f] = (f32x4)0.f;

    // ---------------- layer 1: k=0..255 (h[row] | h[col]) ----------------
    #pragma unroll
    for (int s = 0; s < 8; ++s) {
        s16x8 bf[8];
        #pragma unroll
        for (int f = 0; f < 8; ++f)
            bf[f] = *reinterpret_cast<const s16x8*>(
                W1p + ((s * 4 + g) * DIM + f * 16 + q) * 8);
        #pragma unroll
        for (int mi = 0; mi < 4; ++mi) {
            unsigned off = ((s < 4) ? rbo[mi] : cbo[mi]) + (s & 3) * 64;
            s16x8 a = *reinterpret_cast<const s16x8*>(hb8 + off);
            #pragma unroll
            for (int f = 0; f < 8; ++f) acc[mi][f] = MFMA16(a, bf[f], acc[mi][f]);
        }
    }
    // k=256..287: edge_attr (g<2); k>=272 zero (A=0, W rows zero-padded)
    {
        s16x8 bf[8];
        #pragma unroll
        for (int f = 0; f < 8; ++f)
            bf[f] = *reinterpret_cast<const s16x8*>(
                W1p + ((32 + g) * DIM + f * 16 + q) * 8);
        #pragma unroll
        for (int mi = 0; mi < 4; ++mi) {
            s16x8 a = (s16x8)0;
            if (g < 2) {
                const float4* pe = reinterpret_cast<const float4*>(
                    ea + (size_t)eid4[mi] * EDGE_DIM + g * 8);
                float4 u = pe[0], v = pe[1];
                u32x4 pk;
                pk[0] = cvt_pk_bf16(u.x, u.y); pk[1] = cvt_pk_bf16(u.z, u.w);
                pk[2] = cvt_pk_bf16(v.x, v.y); pk[3] = cvt_pk_bf16(v.z, v.w);
                a = __builtin_bit_cast(s16x8, pk);
            }
            #pragma unroll
            for (int f = 0; f < 8; ++f) acc[mi][f] = MFMA16(a, bf[f], acc[mi][f]);
        }
    }

    // bias + silu -> wave-private swizzled s_H (u32 col-pairs)
    unsigned char* sw = s_u[wv];
    {
        f32x2 b1v[4];
        #pragma unroll
        for (int a = 0; a < 4; ++a)
            b1v[a] = *reinterpret_cast<const f32x2*>(bm1 + a * 32 + 2 * q);
        #pragma unroll
        for (int mi = 0; mi < 4; ++mi)
            #pragma unroll
            for (int r = 0; r < 4; ++r) {
                int e = mi * 16 + g * 4 + r;
                unsigned sx = (unsigned)((e & 7) << 4);
                #pragma unroll
                for (int a = 0; a < 4; ++a) {
                    float v0 = silu_f(acc[mi][2 * a][r]     + b1v[a].x);
                    float v1 = silu_f(acc[mi][2 * a + 1][r] + b1v[a].y);
                    *reinterpret_cast<unsigned*>(
                        sw + e * 256 + ((a * 64 + q * 4) ^ sx)) = cvt_pk_bf16(v0, v1);
                }
            }
    }
    // same-wave LDS RAW -> compiler lgkmcnt; no barrier

    // ---------------- layer 2: k=0..127 ----------------
    f32x4 acc2[4][8];
    #pragma unroll
    for (int mi = 0; mi < 4; ++mi)
        #pragma unroll
        for (int f = 0; f < 8; ++f) acc2[mi][f] = (f32x4)0.f;

    #pragma unroll
    for (int s = 0; s < 4; ++s) {
        s16x8 bf[8];
        #pragma unroll
        for (int f = 0; f < 8; ++f)
            bf[f] = *reinterpret_cast<const s16x8*>(
                W2p + ((s * 4 + g) * DIM + f * 16 + q) * 8);
        #pragma unroll
        for (int mi = 0; mi < 4; ++mi) {
            int e = mi * 16 + q;
            s16x8 a = *reinterpret_cast<const s16x8*>(
                sw + e * 256 + ((s * 64 + g * 16) ^ ((q & 7) << 4)));
            #pragma unroll
            for (int f = 0; f < 8; ++f) acc2[mi][f] = MFMA16(a, bf[f], acc2[mi][f]);
        }
    }

    // bias + silu; wave-local attention dot; sigmoid*mask; pack scaled msgs
    unsigned* smsg = reinterpret_cast<unsigned*>(sw);
    {
        f32x2 b2v[4], wav[4];
        #pragma unroll
        for (int a = 0; a < 4; ++a) {
            b2v[a] = *reinterpret_cast<const f32x2*>(bm2 + a * 32 + 2 * q);
            wav[a] = *reinterpret_cast<const f32x2*>(Wa  + a * 32 + 2 * q);
        }
        const float ba0 = ba[0];
        #pragma unroll
        for (int mi = 0; mi < 4; ++mi)
            #pragma unroll
            for (int r = 0; r < 4; ++r) {
                float p = 0.f;
                #pragma unroll
                for (int a = 0; a < 4; ++a) {
                    float v0 = silu_f(acc2[mi][2 * a][r]     + b2v[a].x);
                    float v1 = silu_f(acc2[mi][2 * a + 1][r] + b2v[a].y);
                    acc2[mi][2 * a][r] = v0; acc2[mi][2 * a + 1][r] = v1;
                    p = fmaf(v0, wav[a].x, fmaf(v1, wav[a].y, p));
                }
                p += __shfl_xor(p, 1);
                p += __shfl_xor(p, 2);
                p += __shfl_xor(p, 4);
                p += __shfl_xor(p, 8);
                int e = mi * 16 + g * 4 + r;
                float mk = __shfl(mskl, e);
                float sc = sigmoid_f(p + ba0) * mk;
                unsigned sx = ((unsigned)(e & 4)) << 2;
                #pragma unroll
                for (int a = 0; a < 4; ++a) {
                    unsigned pk = cvt_pk_bf16(acc2[mi][2 * a][r] * sc,
                                              acc2[mi][2 * a + 1][r] * sc);
                    smsg[e * 64 + ((a * 16 + q) ^ sx)] = pk;
                }
            }
    }

    // segmented run-reduction over the wave's 64 sorted edges.
    // lane = col-pair c: cols {(c>>4)*32 + 2*(c&15), +1}
    {
        const int c = lane;
        float s0 = 0.f, s1 = 0.f;
        int prow = __builtin_amdgcn_readlane(rowl, 0);
        for (int jb = 0; jb < 64; jb += 8) {
            unsigned v[8];
            #pragma unroll
            for (int k = 0; k < 8; ++k)
                v[k] = smsg[(jb + k) * 64 + (c ^ (((jb + k) & 4) << 2))];
            #pragma unroll
            for (int k = 0; k < 8; ++k) {
                int rj = __builtin_amdgcn_readlane(rowl, jb + k);
                if (rj != prow) {                    // wave-uniform branch
                    float* dst = agg + (size_t)prow * DIM + (c >> 4) * 32 + 2 * (c & 15);
                    atomicAdd(dst, s0);
                    atomicAdd(dst + 1, s1);
                    s0 = 0.f; s1 = 0.f; prow = rj;
                }
                s0 += __builtin_bit_cast(float, v[k] << 16);
                s1 += __builtin_bit_cast(float, v[k] & 0xffff0000u);
            }
        }
        float* dst = agg + (size_t)prow * DIM + (c >> 4) * 32 + 2 * (c & 15);
        atomicAdd(dst, s0);
        atomicAdd(dst + 1, s1);
    }
}

// ---------------------------------------------------------------------------
// Node kernel: wave owns 16 nodes x 128 cols; [h|agg] @ Wn1 -> silu -> @Wn2
// -> residual -> flags. No barriers. (small fraction of runtime)
// ---------------------------------------------------------------------------
__global__ __launch_bounds__(256, 4) void node_kernel(
    const unsigned short* __restrict__ h_bf,
    const float* __restrict__ agg,
    const float* __restrict__ h,
    const float* __restrict__ flags,
    const unsigned short* __restrict__ Wn1p,  // 256x128 packed (pair-permuted)
    const float* __restrict__ bn1,
    const unsigned short* __restrict__ Wn2p,  // 128x128 packed (pair-permuted)
    const float* __restrict__ bn2,
    float* __restrict__ out)
{
    __shared__ __align__(16) unsigned char s_u[4][4352];

    const int tid  = threadIdx.x;
    const int wv   = tid >> 6;
    const int lane = tid & 63;
    const int q    = lane & 15;
    const int g    = lane >> 4;
    const int n0w  = blockIdx.x * 64 + wv * 16;

    const int nq  = n0w + q;
    const int nqc = (nq < NN) ? nq : (NN - 1);   // clamp; stores are masked

    f32x4 acc[8];
    #pragma unroll
    for (int f = 0; f < 8; ++f) acc[f] = (f32x4)0.f;

    #pragma unroll
    for (int s = 0; s < 4; ++s) {
        s16x8 a = *reinterpret_cast<const s16x8*>(
            h_bf + (size_t)nqc * DIM + s * 32 + g * 8);
        #pragma unroll
        for (int f = 0; f < 8; ++f) {
            s16x8 b = *reinterpret_cast<const s16x8*>(
                Wn1p + ((s * 4 + g) * DIM + f * 16 + q) * 8);
            acc[f] = MFMA16(a, b, acc[f]);
        }
    }
    #pragma unroll
    for (int s = 4; s < 8; ++s) {
        const float4* pa = reinterpret_cast<const float4*>(
            agg + (size_t)nqc * DIM + (s - 4) * 32 + g * 8);
        float4 u = pa[0], v = pa[1];
        u32x4 pk;
        pk[0] = cvt_pk_bf16(u.x, u.y); pk[1] = cvt_pk_bf16(u.z, u.w);
        pk[2] = cvt_pk_bf16(v.x, v.y); pk[3] = cvt_pk_bf16(v.z, v.w);
        s16x8 a = __builtin_bit_cast(s16x8, pk);
        #pragma unroll
        for (int f = 0; f < 8; ++f) {
            s16x8 b = *reinterpret_cast<const s16x8*>(
                Wn1p + ((s * 4 + g) * DIM + f * 16 + q) * 8);
            acc[f] = MFMA16(a, b, acc[f]);
        }
    }

    unsigned char* sw = s_u[wv];
    {
        #pragma unroll
        for (int aa = 0; aa < 4; ++aa) {
            f32x2 bp = *reinterpret_cast<const f32x2*>(bn1 + aa * 32 + 2 * q);
            #pragma unroll
            for (int r = 0; r < 4; ++r) {
                float v0 = silu_f(acc[2 * aa][r] + bp.x);
                float v1 = silu_f(acc[2 * aa + 1][r] + bp.y);
                *reinterpret_cast<unsigned*>(
                    sw + (g * 4 + r) * 272 + aa * 64 + 4 * q) = cvt_pk_bf16(v0, v1);
            }
        }
    }

    f32x4 acc2[8];
    #pragma unroll
    for (int f = 0; f < 8; ++f) acc2[f] = (f32x4)0.f;

    #pragma unroll
    for (int s = 0; s < 4; ++s) {
        s16x8 a = *reinterpret_cast<const s16x8*>(sw + q * 272 + s * 64 + g * 16);
        #pragma unroll
        for (int f = 0; f < 8; ++f) {
            s16x8 b = *reinterpret_cast<const s16x8*>(
                Wn2p + ((s * 4 + g) * DIM + f * 16 + q) * 8);
            acc2[f] = MFMA16(a, b, acc2[f]);
        }
    }

    {
        #pragma unroll
        for (int r = 0; r < 4; ++r) {
            int n = n0w + 4 * g + r;
            if (n < NN) {
                float fl = flags[n];
                #pragma unroll
                for (int aa = 0; aa < 4; ++aa) {
                    f32x2 b2 = *reinterpret_cast<const f32x2*>(bn2 + aa * 32 + 2 * q);
                    size_t b = (size_t)n * DIM + aa * 32 + 2 * q;
                    f32x2 hv = *reinterpret_cast<const f32x2*>(h + b);
                    f32x2 o;
                    o.x = (hv.x + acc2[2 * aa][r] + b2.x) * fl;
                    o.y = (hv.y + acc2[2 * aa + 1][r] + b2.y) * fl;
                    *reinterpret_cast<f32x2*>(out + b) = o;
                }
            }
        }
    }
}

extern "C" void kernel_launch(void* const* d_in, const int* in_sizes, int n_in,
                              void* d_out, int out_size, void* d_ws, size_t ws_size,
                              hipStream_t stream) {
    const float* h     = (const float*)d_in[0];
    const int*   ei    = (const int*)  d_in[1];
    const float* ea    = (const float*)d_in[2];
    const float* flags = (const float*)d_in[3];
    const float* emask = (const float*)d_in[4];
    const float* Wm1   = (const float*)d_in[5];
    const float* bm1   = (const float*)d_in[6];
    const float* Wm2   = (const float*)d_in[7];
    const float* bm2   = (const float*)d_in[8];
    const float* Wa    = (const float*)d_in[9];
    const float* ba    = (const float*)d_in[10];
    const float* Wn1   = (const float*)d_in[11];
    const float* bn1   = (const float*)d_in[12];
    const float* Wn2   = (const float*)d_in[13];
    const float* bn2   = (const float*)d_in[14];
    float* out = (float*)d_out;

    char* ws = (char*)d_ws;
    float*          agg   = (float*)         (ws);                 // 10,240,000
    unsigned short* h_bf  = (unsigned short*)(ws + 10240000);      //  5,120,000
    unsigned short* W1p   = (unsigned short*)(ws + 15360000);      //     73,728
    unsigned short* W2p   = (unsigned short*)(ws + 15433728);      //     32,768
    unsigned short* Wn1p  = (unsigned short*)(ws + 15466496);      //     65,536
    unsigned short* Wn2p  = (unsigned short*)(ws + 15532032);      //     32,768
    int*            cnts  = (int*)           (ws + 15564800);      //     80,000
    int*            eidS  = (int*)           (ws + 15644800);      //  2,560,000
    unsigned short* rowS  = (unsigned short*)(ws + 18204800);      //  1,280,000
    const size_t WS_NEED = 19484800;

    const bool sorted = (ws_size >= WS_NEED);

    prep_all_kernel<<<5479, 256, 0, stream>>>(h, h_bf, Wm1, Wm2, Wn1, Wn2,
                                              W1p, W2p, Wn1p, Wn2p, agg, cnts);

    if (sorted) {
        hist_kernel<<<(E_TOT + 255) / 256, 256, 0, stream>>>(ei, cnts);
        scan_kernel<<<1, 1024, 0, stream>>>(cnts);
        scatter_kernel<<<(E_TOT + 255) / 256, 256, 0, stream>>>(ei, cnts, eidS, rowS);
        edge_kernel<true><<<E_TOT / 256, 256, 0, stream>>>(
            h_bf, ei, eidS, rowS, ea, emask, W1p, bm1, W2p, bm2, Wa, ba, agg);
    } else {
        edge_kernel<false><<<E_TOT / 256, 256, 0, stream>>>(
            h_bf, ei, eidS, rowS, ea, emask, W1p, bm1, W2p, bm2, Wa, ba, agg);
    }

    node_kernel<<<(NN + 63) / 64, 256, 0, stream>>>(h_bf, agg, h, flags,
                                                    Wn1p, bn1, Wn2p, bn2, out);
}

// Round 7
// 289.434 us; speedup vs baseline: 1.0967x; 1.0951x over previous
//
#include <hip/hip_runtime.h>
#include <math.h>

#define E_TOT   640000
#define NN      20000
#define DIM     128
#define EDGE_DIM 16

typedef float f32x4 __attribute__((ext_vector_type(4)));
typedef float f32x2 __attribute__((ext_vector_type(2)));
typedef short s16x8 __attribute__((ext_vector_type(8)));
typedef unsigned u32x4 __attribute__((ext_vector_type(4)));
typedef __bf16 bfx8 __attribute__((ext_vector_type(8)));

__device__ __forceinline__ unsigned short f2bf(float f) {
    unsigned u = __builtin_bit_cast(unsigned, f);
    u += 0x7fffu + ((u >> 16) & 1u);
    return (unsigned short)(u >> 16);
}
__device__ __forceinline__ unsigned cvt_pk_bf16(float lo, float hi) {
    unsigned r;
    asm("v_cvt_pk_bf16_f32 %0, %1, %2" : "=v"(r) : "v"(lo), "v"(hi));
    return r;
}
// fast transcendentals: harness compiles WITHOUT -ffast-math, so x/(1+e)
// emits IEEE div (~15 VALU ops). v_exp_f32 (=2^x) + v_rcp_f32 (~1ulp) cut
// silu from ~16 ops to 5; outputs are bf16 so precision is ample.
__device__ __forceinline__ float fast_exp2(float x) {
    float r; asm("v_exp_f32 %0, %1" : "=v"(r) : "v"(x)); return r;
}
__device__ __forceinline__ float fast_rcp(float x) {
    float r; asm("v_rcp_f32 %0, %1" : "=v"(r) : "v"(x)); return r;
}
#define LOG2E 1.44269504f
__device__ __forceinline__ float silu_f(float x) {
    return x * fast_rcp(1.0f + fast_exp2(-LOG2E * x));
}
__device__ __forceinline__ float sigmoid_f(float x) {
    return fast_rcp(1.0f + fast_exp2(-LOG2E * x));
}

#define MFMA16(a, b, c) __builtin_amdgcn_mfma_f32_16x16x32_bf16( \
    __builtin_bit_cast(bfx8, (a)), __builtin_bit_cast(bfx8, (b)), (c), 0, 0, 0)

// ---------------------------------------------------------------------------
// mega-prep: h->bf16, 4 weight packs (pair-permuted fragment-major), zero
// agg and cnts. Pack: Wp[(sg*128 + f*16 + q)*8 + t] = W[k=sg*8+t][col],
// col = (f>>1)*32 + 2q + (f&1); zero-padded for k >= K.
// ---------------------------------------------------------------------------
__device__ __forceinline__ void pack_w(const float* __restrict__ W,
                                       unsigned short* __restrict__ Wp,
                                       int K, int id) {
    int t   = id & 7;
    int pos = (id >> 3) & 127;
    int sg  = id >> 10;
    int qq = pos & 15, f = pos >> 4;
    int col = (f >> 1) * 32 + 2 * qq + (f & 1);
    int k = sg * 8 + t;
    Wp[id] = (k < K) ? f2bf(W[(size_t)k * DIM + col]) : (unsigned short)0;
}

__global__ void prep_all_kernel(const float* __restrict__ h,
                                unsigned short* __restrict__ h_bf,
                                const float* __restrict__ Wm1,
                                const float* __restrict__ Wm2,
                                const float* __restrict__ Wn1,
                                const float* __restrict__ Wn2,
                                unsigned short* __restrict__ W1p,
                                unsigned short* __restrict__ W2p,
                                unsigned short* __restrict__ Wn1p,
                                unsigned short* __restrict__ Wn2p,
                                float* __restrict__ agg,
                                int* __restrict__ cnts) {
    const int blk = blockIdx.x;
    const int tid = threadIdx.x;
    if (blk < 2500) {                       // h -> bf16 (640000 f32x4)
        int i = blk * 256 + tid;
        float4 v = reinterpret_cast<const float4*>(h)[i];
        unsigned short* d = h_bf + i * 4;
        d[0] = f2bf(v.x); d[1] = f2bf(v.y); d[2] = f2bf(v.z); d[3] = f2bf(v.w);
    } else if (blk < 2644) {                // W1p: 288x128
        pack_w(Wm1, W1p, 272, (blk - 2500) * 256 + tid);
    } else if (blk < 2708) {                // W2p: 128x128
        pack_w(Wm2, W2p, 128, (blk - 2644) * 256 + tid);
    } else if (blk < 2836) {                // Wn1p: 256x128
        pack_w(Wn1, Wn1p, 256, (blk - 2708) * 256 + tid);
    } else if (blk < 2900) {                // Wn2p: 128x128
        pack_w(Wn2, Wn2p, 128, (blk - 2836) * 256 + tid);
    } else if (blk < 5400) {                // zero agg (640000 f32x4)
        int i = (blk - 2900) * 256 + tid;
        reinterpret_cast<f32x4*>(agg)[i] = (f32x4)0.f;
    } else {                                // zero cnts (20000 ints)
        int i = (blk - 5400) * 256 + tid;
        if (i < NN) cnts[i] = 0;
    }
}

// ---------------------------------------------------------------------------
// counting sort of edges by row
// ---------------------------------------------------------------------------
__global__ void hist_kernel(const int* __restrict__ ei, int* __restrict__ counts) {
    int e = blockIdx.x * blockDim.x + threadIdx.x;
    if (e < E_TOT) atomicAdd(&counts[ei[e]], 1);
}

__global__ __launch_bounds__(1024) void scan_kernel(int* __restrict__ counts) {
    __shared__ int s[1024];
    const int tid = threadIdx.x;
    const int CH = 20;
    int base = tid * CH;
    int loc[CH];
    int sum = 0;
    #pragma unroll
    for (int i = 0; i < CH; ++i) {
        int idx = base + i;
        loc[i] = (idx < NN) ? counts[idx] : 0;
        sum += loc[i];
    }
    s[tid] = sum;
    __syncthreads();
    for (int off = 1; off < 1024; off <<= 1) {
        int v = (tid >= off) ? s[tid - off] : 0;
        __syncthreads();
        s[tid] += v;
        __syncthreads();
    }
    int run = s[tid] - sum;
    #pragma unroll
    for (int i = 0; i < CH; ++i) {
        int idx = base + i;
        if (idx < NN) counts[idx] = run;
        run += loc[i];
    }
}

__global__ void scatter_kernel(const int* __restrict__ ei, int* __restrict__ cursor,
                               int* __restrict__ eidS, unsigned short* __restrict__ rowS) {
    int e = blockIdx.x * blockDim.x + threadIdx.x;
    if (e < E_TOT) {
        int r = ei[e];
        int p = atomicAdd(&cursor[r], 1);
        eidS[p] = e;
        rowS[p] = (unsigned short)r;
    }
}

// ---------------------------------------------------------------------------
// Edge kernel: 4 waves/block, wave owns 64 edges x ALL 128 cols. Identical
// structure to r6 (zero barriers, wave-private swizzled LDS, segmented
// run-reduction); only the transcendental cost changed (fast silu/sigmoid).
// ---------------------------------------------------------------------------
template<bool SORTED>
__global__ __launch_bounds__(256, 2) void edge_kernel(
    const unsigned short* __restrict__ h_bf,
    const int* __restrict__ ei,
    const int* __restrict__ eidS,
    const unsigned short* __restrict__ rowS,
    const float* __restrict__ ea,
    const float* __restrict__ emask,
    const unsigned short* __restrict__ W1p,  // 288x128 packed (pair-permuted)
    const float* __restrict__ bm1,
    const unsigned short* __restrict__ W2p,  // 128x128 packed (pair-permuted)
    const float* __restrict__ bm2,
    const float* __restrict__ Wa, const float* __restrict__ ba,
    float* __restrict__ agg)
{
    __shared__ __align__(16) unsigned char s_u[4][16384];  // wave-private

    const int tid  = threadIdx.x;
    const int wv   = tid >> 6;
    const int lane = tid & 63;
    const int q    = lane & 15;
    const int g    = lane >> 4;
    const int e0w  = blockIdx.x * 256 + wv * 64;

    // per-lane meta: lane l holds edge (e0w + l)
    const int   eidl = SORTED ? eidS[e0w + lane] : (e0w + lane);
    const int   rowl = SORTED ? (int)rowS[e0w + lane] : ei[eidl];
    const int   coll = ei[E_TOT + eidl];
    const float mskl = emask[eidl];

    // per-mi byte offsets (lane (q,g) computes for edge mi*16+q)
    unsigned rbo[4], cbo[4];
    int eid4[4];
    #pragma unroll
    for (int mi = 0; mi < 4; ++mi) {
        int src = mi * 16 + q;
        rbo[mi]  = (unsigned)__shfl(rowl, src) * 256u + g * 16u;
        cbo[mi]  = (unsigned)__shfl(coll, src) * 256u + g * 16u;
        eid4[mi] = __shfl(eidl, src);
    }
    const char* hb8 = reinterpret_cast<const char*>(h_bf);

    f32x4 acc[4][8];
    #pragma unroll
    for (int mi = 0; mi < 4; ++mi)
        #pragma unroll
        for (int f = 0; f < 8; ++f) acc[mi][f] = (f32x4)0.f;

    // ---------------- layer 1: k=0..255 (h[row] | h[col]) ----------------
    #pragma unroll
    for (int s = 0; s < 8; ++s) {
        s16x8 bf[8];
        #pragma unroll
        for (int f = 0; f < 8; ++f)
            bf[f] = *reinterpret_cast<const s16x8*>(
                W1p + ((s * 4 + g) * DIM + f * 16 + q) * 8);
        #pragma unroll
        for (int mi = 0; mi < 4; ++mi) {
            unsigned off = ((s < 4) ? rbo[mi] : cbo[mi]) + (s & 3) * 64;
            s16x8 a = *reinterpret_cast<const s16x8*>(hb8 + off);
            #pragma unroll
            for (int f = 0; f < 8; ++f) acc[mi][f] = MFMA16(a, bf[f], acc[mi][f]);
        }
    }
    // k=256..287: edge_attr (g<2); k>=272 zero (A=0, W rows zero-padded)
    {
        s16x8 bf[8];
        #pragma unroll
        for (int f = 0; f < 8; ++f)
            bf[f] = *reinterpret_cast<const s16x8*>(
                W1p + ((32 + g) * DIM + f * 16 + q) * 8);
        #pragma unroll
        for (int mi = 0; mi < 4; ++mi) {
            s16x8 a = (s16x8)0;
            if (g < 2) {
                const float4* pe = reinterpret_cast<const float4*>(
                    ea + (size_t)eid4[mi] * EDGE_DIM + g * 8);
                float4 u = pe[0], v = pe[1];
                u32x4 pk;
                pk[0] = cvt_pk_bf16(u.x, u.y); pk[1] = cvt_pk_bf16(u.z, u.w);
                pk[2] = cvt_pk_bf16(v.x, v.y); pk[3] = cvt_pk_bf16(v.z, v.w);
                a = __builtin_bit_cast(s16x8, pk);
            }
            #pragma unroll
            for (int f = 0; f < 8; ++f) acc[mi][f] = MFMA16(a, bf[f], acc[mi][f]);
        }
    }

    // bias + silu -> wave-private swizzled s_H (u32 col-pairs)
    unsigned char* sw = s_u[wv];
    {
        f32x2 b1v[4];
        #pragma unroll
        for (int a = 0; a < 4; ++a)
            b1v[a] = *reinterpret_cast<const f32x2*>(bm1 + a * 32 + 2 * q);
        #pragma unroll
        for (int mi = 0; mi < 4; ++mi)
            #pragma unroll
            for (int r = 0; r < 4; ++r) {
                int e = mi * 16 + g * 4 + r;
                unsigned sx = (unsigned)((e & 7) << 4);
                #pragma unroll
                for (int a = 0; a < 4; ++a) {
                    float v0 = silu_f(acc[mi][2 * a][r]     + b1v[a].x);
                    float v1 = silu_f(acc[mi][2 * a + 1][r] + b1v[a].y);
                    *reinterpret_cast<unsigned*>(
                        sw + e * 256 + ((a * 64 + q * 4) ^ sx)) = cvt_pk_bf16(v0, v1);
                }
            }
    }
    // same-wave LDS RAW -> compiler lgkmcnt; no barrier

    // ---------------- layer 2: k=0..127 ----------------
    f32x4 acc2[4][8];
    #pragma unroll
    for (int mi = 0; mi < 4; ++mi)
        #pragma unroll
        for (int f = 0; f < 8; ++f) acc2[mi][f] = (f32x4)0.f;

    #pragma unroll
    for (int s = 0; s < 4; ++s) {
        s16x8 bf[8];
        #pragma unroll
        for (int f = 0; f < 8; ++f)
            bf[f] = *reinterpret_cast<const s16x8*>(
                W2p + ((s * 4 + g) * DIM + f * 16 + q) * 8);
        #pragma unroll
        for (int mi = 0; mi < 4; ++mi) {
            int e = mi * 16 + q;
            s16x8 a = *reinterpret_cast<const s16x8*>(
                sw + e * 256 + ((s * 64 + g * 16) ^ ((q & 7) << 4)));
            #pragma unroll
            for (int f = 0; f < 8; ++f) acc2[mi][f] = MFMA16(a, bf[f], acc2[mi][f]);
        }
    }

    // bias + silu; wave-local attention dot; sigmoid*mask; pack scaled msgs
    unsigned* smsg = reinterpret_cast<unsigned*>(sw);
    {
        f32x2 b2v[4], wav[4];
        #pragma unroll
        for (int a = 0; a < 4; ++a) {
            b2v[a] = *reinterpret_cast<const f32x2*>(bm2 + a * 32 + 2 * q);
            wav[a] = *reinterpret_cast<const f32x2*>(Wa  + a * 32 + 2 * q);
        }
        const float ba0 = ba[0];
        #pragma unroll
        for (int mi = 0; mi < 4; ++mi)
            #pragma unroll
            for (int r = 0; r < 4; ++r) {
                float p = 0.f;
                #pragma unroll
                for (int a = 0; a < 4; ++a) {
                    float v0 = silu_f(acc2[mi][2 * a][r]     + b2v[a].x);
                    float v1 = silu_f(acc2[mi][2 * a + 1][r] + b2v[a].y);
                    acc2[mi][2 * a][r] = v0; acc2[mi][2 * a + 1][r] = v1;
                    p = fmaf(v0, wav[a].x, fmaf(v1, wav[a].y, p));
                }
                p += __shfl_xor(p, 1);
                p += __shfl_xor(p, 2);
                p += __shfl_xor(p, 4);
                p += __shfl_xor(p, 8);
                int e = mi * 16 + g * 4 + r;
                float mk = __shfl(mskl, e);
                float sc = sigmoid_f(p + ba0) * mk;
                unsigned sx = ((unsigned)(e & 4)) << 2;
                #pragma unroll
                for (int a = 0; a < 4; ++a) {
                    unsigned pk = cvt_pk_bf16(acc2[mi][2 * a][r] * sc,
                                              acc2[mi][2 * a + 1][r] * sc);
                    smsg[e * 64 + ((a * 16 + q) ^ sx)] = pk;
                }
            }
    }

    // segmented run-reduction over the wave's 64 sorted edges.
    // lane = col-pair c: cols {(c>>4)*32 + 2*(c&15), +1}
    {
        const int c = lane;
        float s0 = 0.f, s1 = 0.f;
        int prow = __builtin_amdgcn_readlane(rowl, 0);
        for (int jb = 0; jb < 64; jb += 8) {
            unsigned v[8];
            #pragma unroll
            for (int k = 0; k < 8; ++k)
                v[k] = smsg[(jb + k) * 64 + (c ^ (((jb + k) & 4) << 2))];
            #pragma unroll
            for (int k = 0; k < 8; ++k) {
                int rj = __builtin_amdgcn_readlane(rowl, jb + k);
                if (rj != prow) {                    // wave-uniform branch
                    float* dst = agg + (size_t)prow * DIM + (c >> 4) * 32 + 2 * (c & 15);
                    atomicAdd(dst, s0);
                    atomicAdd(dst + 1, s1);
                    s0 = 0.f; s1 = 0.f; prow = rj;
                }
                s0 += __builtin_bit_cast(float, v[k] << 16);
                s1 += __builtin_bit_cast(float, v[k] & 0xffff0000u);
            }
        }
        float* dst = agg + (size_t)prow * DIM + (c >> 4) * 32 + 2 * (c & 15);
        atomicAdd(dst, s0);
        atomicAdd(dst + 1, s1);
    }
}

// ---------------------------------------------------------------------------
// Node kernel: wave owns 16 nodes x 128 cols; [h|agg] @ Wn1 -> silu -> @Wn2
// -> residual -> flags. No barriers. Fast silu.
// ---------------------------------------------------------------------------
__global__ __launch_bounds__(256, 4) void node_kernel(
    const unsigned short* __restrict__ h_bf,
    const float* __restrict__ agg,
    const float* __restrict__ h,
    const float* __restrict__ flags,
    const unsigned short* __restrict__ Wn1p,  // 256x128 packed (pair-permuted)
    const float* __restrict__ bn1,
    const unsigned short* __restrict__ Wn2p,  // 128x128 packed (pair-permuted)
    const float* __restrict__ bn2,
    float* __restrict__ out)
{
    __shared__ __align__(16) unsigned char s_u[4][4352];

    const int tid  = threadIdx.x;
    const int wv   = tid >> 6;
    const int lane = tid & 63;
    const int q    = lane & 15;
    const int g    = lane >> 4;
    const int n0w  = blockIdx.x * 64 + wv * 16;

    const int nq  = n0w + q;
    const int nqc = (nq < NN) ? nq : (NN - 1);   // clamp; stores are masked

    f32x4 acc[8];
    #pragma unroll
    for (int f = 0; f < 8; ++f) acc[f] = (f32x4)0.f;

    #pragma unroll
    for (int s = 0; s < 4; ++s) {
        s16x8 a = *reinterpret_cast<const s16x8*>(
            h_bf + (size_t)nqc * DIM + s * 32 + g * 8);
        #pragma unroll
        for (int f = 0; f < 8; ++f) {
            s16x8 b = *reinterpret_cast<const s16x8*>(
                Wn1p + ((s * 4 + g) * DIM + f * 16 + q) * 8);
            acc[f] = MFMA16(a, b, acc[f]);
        }
    }
    #pragma unroll
    for (int s = 4; s < 8; ++s) {
        const float4* pa = reinterpret_cast<const float4*>(
            agg + (size_t)nqc * DIM + (s - 4) * 32 + g * 8);
        float4 u = pa[0], v = pa[1];
        u32x4 pk;
        pk[0] = cvt_pk_bf16(u.x, u.y); pk[1] = cvt_pk_bf16(u.z, u.w);
        pk[2] = cvt_pk_bf16(v.x, v.y); pk[3] = cvt_pk_bf16(v.z, v.w);
        s16x8 a = __builtin_bit_cast(s16x8, pk);
        #pragma unroll
        for (int f = 0; f < 8; ++f) {
            s16x8 b = *reinterpret_cast<const s16x8*>(
                Wn1p + ((s * 4 + g) * DIM + f * 16 + q) * 8);
            acc[f] = MFMA16(a, b, acc[f]);
        }
    }

    unsigned char* sw = s_u[wv];
    {
        #pragma unroll
        for (int aa = 0; aa < 4; ++aa) {
            f32x2 bp = *reinterpret_cast<const f32x2*>(bn1 + aa * 32 + 2 * q);
            #pragma unroll
            for (int r = 0; r < 4; ++r) {
                float v0 = silu_f(acc[2 * aa][r] + bp.x);
                float v1 = silu_f(acc[2 * aa + 1][r] + bp.y);
                *reinterpret_cast<unsigned*>(
                    sw + (g * 4 + r) * 272 + aa * 64 + 4 * q) = cvt_pk_bf16(v0, v1);
            }
        }
    }

    f32x4 acc2[8];
    #pragma unroll
    for (int f = 0; f < 8; ++f) acc2[f] = (f32x4)0.f;

    #pragma unroll
    for (int s = 0; s < 4; ++s) {
        s16x8 a = *reinterpret_cast<const s16x8*>(sw + q * 272 + s * 64 + g * 16);
        #pragma unroll
        for (int f = 0; f < 8; ++f) {
            s16x8 b = *reinterpret_cast<const s16x8*>(
                Wn2p + ((s * 4 + g) * DIM + f * 16 + q) * 8);
            acc2[f] = MFMA16(a, b, acc2[f]);
        }
    }

    {
        #pragma unroll
        for (int r = 0; r < 4; ++r) {
            int n = n0w + 4 * g + r;
            if (n < NN) {
                float fl = flags[n];
                #pragma unroll
                for (int aa = 0; aa < 4; ++aa) {
                    f32x2 b2 = *reinterpret_cast<const f32x2*>(bn2 + aa * 32 + 2 * q);
                    size_t b = (size_t)n * DIM + aa * 32 + 2 * q;
                    f32x2 hv = *reinterpret_cast<const f32x2*>(h + b);
                    f32x2 o;
                    o.x = (hv.x + acc2[2 * aa][r] + b2.x) * fl;
                    o.y = (hv.y + acc2[2 * aa + 1][r] + b2.y) * fl;
                    *reinterpret_cast<f32x2*>(out + b) = o;
                }
            }
        }
    }
}

extern "C" void kernel_launch(void* const* d_in, const int* in_sizes, int n_in,
                              void* d_out, int out_size, void* d_ws, size_t ws_size,
                              hipStream_t stream) {
    const float* h     = (const float*)d_in[0];
    const int*   ei    = (const int*)  d_in[1];
    const float* ea    = (const float*)d_in[2];
    const float* flags = (const float*)d_in[3];
    const float* emask = (const float*)d_in[4];
    const float* Wm1   = (const float*)d_in[5];
    const float* bm1   = (const float*)d_in[6];
    const float* Wm2   = (const float*)d_in[7];
    const float* bm2   = (const float*)d_in[8];
    const float* Wa    = (const float*)d_in[9];
    const float* ba    = (const float*)d_in[10];
    const float* Wn1   = (const float*)d_in[11];
    const float* bn1   = (const float*)d_in[12];
    const float* Wn2   = (const float*)d_in[13];
    const float* bn2   = (const float*)d_in[14];
    float* out = (float*)d_out;

    char* ws = (char*)d_ws;
    float*          agg   = (float*)         (ws);                 // 10,240,000
    unsigned short* h_bf  = (unsigned short*)(ws + 10240000);      //  5,120,000
    unsigned short* W1p   = (unsigned short*)(ws + 15360000);      //     73,728
    unsigned short* W2p   = (unsigned short*)(ws + 15433728);      //     32,768
    unsigned short* Wn1p  = (unsigned short*)(ws + 15466496);      //     65,536
    unsigned short* Wn2p  = (unsigned short*)(ws + 15532032);      //     32,768
    int*            cnts  = (int*)           (ws + 15564800);      //     80,000
    int*            eidS  = (int*)           (ws + 15644800);      //  2,560,000
    unsigned short* rowS  = (unsigned short*)(ws + 18204800);      //  1,280,000
    const size_t WS_NEED = 19484800;

    const bool sorted = (ws_size >= WS_NEED);

    prep_all_kernel<<<5479, 256, 0, stream>>>(h, h_bf, Wm1, Wm2, Wn1, Wn2,
                                              W1p, W2p, Wn1p, Wn2p, agg, cnts);

    if (sorted) {
        hist_kernel<<<(E_TOT + 255) / 256, 256, 0, stream>>>(ei, cnts);
        scan_kernel<<<1, 1024, 0, stream>>>(cnts);
        scatter_kernel<<<(E_TOT + 255) / 256, 256, 0, stream>>>(ei, cnts, eidS, rowS);
        edge_kernel<true><<<E_TOT / 256, 256, 0, stream>>>(
            h_bf, ei, eidS, rowS, ea, emask, W1p, bm1, W2p, bm2, Wa, ba, agg);
    } else {
        edge_kernel<false><<<E_TOT / 256, 256, 0, stream>>>(
            h_bf, ei, eidS, rowS, ea, emask, W1p, bm1, W2p, bm2, Wa, ba, agg);
    }

    node_kernel<<<(NN + 63) / 64, 256, 0, stream>>>(h_bf, agg, h, flags,
                                                    Wn1p, bn1, Wn2p, bn2, out);
}